// Round 1
// baseline (16554.192 us; speedup 1.0000x reference)
//
#include <hip/hip_runtime.h>
#include <hip/hip_bf16.h>

#define B_ 16
#define S_ 512
#define H_ 512
#define V_ 10000
#define G_ 2048
#define M_ (B_*S_)   // 8192 tokens

typedef short bf16x8 __attribute__((ext_vector_type(8)));
typedef float f32x4 __attribute__((ext_vector_type(4)));
typedef _Float16 f16x2 __attribute__((ext_vector_type(2)));

#define BC2(u) __builtin_bit_cast(f16x2, (unsigned int)(u))

#if __has_builtin(__builtin_amdgcn_fdot2)
#define FDOT2(a, b, c) __builtin_amdgcn_fdot2((a), (b), (c), false)
#else
#define FDOT2(a, b, c) ((c) + (float)(a)[0]*(float)(b)[0] + (float)(a)[1]*(float)(b)[1])
#endif

static __device__ __forceinline__ unsigned short f2bf(float x) {
    union { float f; unsigned int u; } v; v.f = x;
    unsigned int r = v.u + 0x7fffu + ((v.u >> 16) & 1u);   // RNE
    return (unsigned short)(r >> 16);
}

// ---------------------------------------------------------------------------
// prep: fp32 weights -> bf16 (GEMM operands), w_hh -> f16 in k-chunk-major
// layout [64][2048] of uint4 (8 halves) so recurrent loads coalesce.
// Also combined biases b_ih + b_hh.
// ---------------------------------------------------------------------------
__global__ void prep_kernel(const float* __restrict__ w_ih0, const float* __restrict__ w_hh0,
                            const float* __restrict__ b_ih0, const float* __restrict__ b_hh0,
                            const float* __restrict__ w_ih1, const float* __restrict__ w_hh1,
                            const float* __restrict__ b_ih1, const float* __restrict__ b_hh1,
                            const float* __restrict__ w1,   const float* __restrict__ w2,
                            unsigned short* __restrict__ w_ih0_b, _Float16* __restrict__ w_hh0_h,
                            unsigned short* __restrict__ w_ih1_b, _Float16* __restrict__ w_hh1_h,
                            unsigned short* __restrict__ w1_b,    unsigned short* __restrict__ w2_b,
                            float* __restrict__ bias0, float* __restrict__ bias1) {
    int i  = blockIdx.x * blockDim.x + threadIdx.x;
    int st = gridDim.x * blockDim.x;
    for (int k = i; k < G_*H_; k += st) {
        w_ih0_b[k] = f2bf(w_ih0[k]);
        w_ih1_b[k] = f2bf(w_ih1[k]);
        // dst half-index d = (kc*2048 + row)*8 + w ; src = row*512 + kc*8 + w
        int row = (k >> 3) & (G_-1);
        int kc  = k >> 14;
        int w   = k & 7;
        int s   = row*H_ + kc*8 + w;
        w_hh0_h[k] = (_Float16)w_hh0[s];
        w_hh1_h[k] = (_Float16)w_hh1[s];
    }
    for (int k = i; k < V_*128; k += st) w2_b[k] = f2bf(w2[k]);
    for (int k = i; k < 128*H_; k += st) w1_b[k] = f2bf(w1[k]);
    for (int k = i; k < G_;     k += st) { bias0[k] = b_ih0[k] + b_hh0[k]; bias1[k] = b_ih1[k] + b_hh1[k]; }
}

// ---------------------------------------------------------------------------
// embed: emb[m][h] = w_emb[h][src[m]] + b_emb[h]  (bf16 out)
// ---------------------------------------------------------------------------
__global__ void embed_kernel(const int* __restrict__ src, const float* __restrict__ w_emb,
                             const float* __restrict__ b_emb, unsigned short* __restrict__ emb) {
    int m = blockIdx.x;
    int idx = src[m];
    for (int h = threadIdx.x; h < H_; h += blockDim.x)
        emb[(long)m*H_ + h] = f2bf(w_emb[(long)h*V_ + idx] + b_emb[h]);
}

// ---------------------------------------------------------------------------
// Generic bf16 MFMA GEMM: C[M,N] = A[M,K] @ B[N,K]^T + bias[N]
// 128x128 tile, BK=32, 256 threads (4 waves in 2x2, each 64x64 -> 4x4 MFMA tiles)
// LDS row stride 40 elems (80 B): 16B-aligned b128 frag reads, <=2-way banks.
// ---------------------------------------------------------------------------
template<bool RELU, bool OUT_BF16>
__launch_bounds__(256)
__global__ void gemm_kernel(const unsigned short* __restrict__ A, const unsigned short* __restrict__ Bm,
                            const float* __restrict__ bias, void* __restrict__ Cout,
                            int Ndim, int K) {
    __shared__ unsigned short At[128*40];
    __shared__ unsigned short Bt[128*40];
    int m0 = blockIdx.y * 128;
    int n0 = blockIdx.x * 128;
    int tid  = threadIdx.x;
    int lane = tid & 63, wave = tid >> 6;
    int wm = (wave >> 1) * 64, wn = (wave & 1) * 64;
    int l15 = lane & 15, l4 = lane >> 4;
    f32x4 acc[4][4] = {};

    for (int kk = 0; kk < K; kk += 32) {
        __syncthreads();   // protect LDS against previous iteration's frag reads
        #pragma unroll
        for (int rep = 0; rep < 2; ++rep) {
            int gid = tid + rep*256;          // 0..511 : 128 rows x 4 groups of 8 bf16
            int row = gid >> 2, c8 = (gid & 3) << 3;
            *(uint4*)&At[row*40 + c8] = *(const uint4*)&A[(long)(m0+row)*K + kk + c8];
            int nrow = n0 + row; if (nrow >= Ndim) nrow = Ndim - 1;   // clamp (values unused)
            *(uint4*)&Bt[row*40 + c8] = *(const uint4*)&Bm[(long)nrow*K + kk + c8];
        }
        __syncthreads();
        bf16x8 af[4], bfr[4];
        #pragma unroll
        for (int i = 0; i < 4; ++i)
            af[i] = *(const bf16x8*)&At[(wm + i*16 + l15)*40 + l4*8];
        #pragma unroll
        for (int j = 0; j < 4; ++j)
            bfr[j] = *(const bf16x8*)&Bt[(wn + j*16 + l15)*40 + l4*8];
        #pragma unroll
        for (int i = 0; i < 4; ++i)
            #pragma unroll
            for (int j = 0; j < 4; ++j)
                acc[i][j] = __builtin_amdgcn_mfma_f32_16x16x32_bf16(af[i], bfr[j], acc[i][j], 0, 0, 0);
    }

    #pragma unroll
    for (int i = 0; i < 4; ++i) {
        int row = m0 + wm + i*16 + l4*4;
        #pragma unroll
        for (int j = 0; j < 4; ++j) {
            int col = n0 + wn + j*16 + l15;
            if (col < Ndim) {
                float bv = bias[col];
                #pragma unroll
                for (int r = 0; r < 4; ++r) {
                    float v = acc[i][j][r] + bv;
                    if (RELU) v = v > 0.f ? v : 0.f;
                    if (OUT_BF16) ((unsigned short*)Cout)[(long)(row+r)*Ndim + col] = f2bf(v);
                    else          ((float*)Cout)[(long)(row+r)*Ndim + col] = v;
                }
            }
        }
    }
}

// ---------------------------------------------------------------------------
// LSTM layer: one block per chain (batch element), 1024 threads.
// Thread tid owns gate rows {tid, tid+1024}; gates via v_dot2_f32_f16 against
// h (f16, LDS-broadcast). Elementwise (threads<512) keeps c in registers.
// Weights pre-transposed: wT[k][row] uint4 -> fully coalesced streams (L2-res).
// ---------------------------------------------------------------------------
__launch_bounds__(1024)
__global__ void lstm_kernel(const float* __restrict__ xp, const uint4* __restrict__ wT,
                            unsigned short* __restrict__ hout) {
    __shared__ _Float16 hsh[H_];
    __shared__ float    gsh[G_];
    int b   = blockIdx.x;
    int tid = threadIdx.x;
    int r1  = tid + 1024;
    float c = 0.f;
    if (tid < H_) hsh[tid] = (_Float16)0.f;
    __syncthreads();
    const f16x2* h2 = (const f16x2*)hsh;

    for (int t = 0; t < S_; ++t) {
        const float* xr = xp + ((long)b*S_ + t) * G_;
        float acc0[4] = {0.f,0.f,0.f,0.f}, acc1[4] = {0.f,0.f,0.f,0.f};
        #pragma unroll 4
        for (int k = 0; k < 64; ++k) {
            uint4 wa = wT[k*G_ + tid];
            uint4 wb = wT[k*G_ + r1];
            f16x2 ha = h2[k*4+0], hb = h2[k*4+1], hc = h2[k*4+2], hd = h2[k*4+3];
            acc0[0] = FDOT2(BC2(wa.x), ha, acc0[0]);
            acc0[1] = FDOT2(BC2(wa.y), hb, acc0[1]);
            acc0[2] = FDOT2(BC2(wa.z), hc, acc0[2]);
            acc0[3] = FDOT2(BC2(wa.w), hd, acc0[3]);
            acc1[0] = FDOT2(BC2(wb.x), ha, acc1[0]);
            acc1[1] = FDOT2(BC2(wb.y), hb, acc1[1]);
            acc1[2] = FDOT2(BC2(wb.z), hc, acc1[2]);
            acc1[3] = FDOT2(BC2(wb.w), hd, acc1[3]);
        }
        gsh[tid] = xr[tid] + acc0[0]+acc0[1]+acc0[2]+acc0[3];
        gsh[r1]  = xr[r1]  + acc1[0]+acc1[1]+acc1[2]+acc1[3];
        __syncthreads();
        if (tid < H_) {
            float xi = gsh[tid], xf = gsh[tid+512], xg = gsh[tid+1024], xo = gsh[tid+1536];
            float ig = 1.f/(1.f+__expf(-xi));
            float fg = 1.f/(1.f+__expf(-xf));
            float gg = tanhf(xg);
            float og = 1.f/(1.f+__expf(-xo));
            c = fg*c + ig*gg;
            float h = og*tanhf(c);
            hsh[tid] = (_Float16)h;
            hout[((long)b*S_ + t)*H_ + tid] = f2bf(h);
        }
        __syncthreads();
    }
}

// ---------------------------------------------------------------------------
extern "C" void kernel_launch(void* const* d_in, const int* in_sizes, int n_in,
                              void* d_out, int out_size, void* d_ws, size_t ws_size,
                              hipStream_t stream) {
    const int*   src   = (const int*)  d_in[0];
    const float* w_emb = (const float*)d_in[1];
    const float* b_emb = (const float*)d_in[2];
    const float* w_ih0 = (const float*)d_in[3];
    const float* w_hh0 = (const float*)d_in[4];
    const float* b_ih0 = (const float*)d_in[5];
    const float* b_hh0 = (const float*)d_in[6];
    const float* w_ih1 = (const float*)d_in[7];
    const float* w_hh1 = (const float*)d_in[8];
    const float* b_ih1 = (const float*)d_in[9];
    const float* b_hh1 = (const float*)d_in[10];
    const float* w1    = (const float*)d_in[11];
    const float* b1    = (const float*)d_in[12];
    const float* w2    = (const float*)d_in[13];
    const float* b2    = (const float*)d_in[14];
    float* out = (float*)d_out;

    char* ws = (char*)d_ws;
    size_t off = 0;
    auto alloc = [&](size_t bytes) -> void* {
        void* p = ws + off;
        off = (off + bytes + 255) & ~(size_t)255;
        return p;
    };
    unsigned short* w_ih0_b = (unsigned short*)alloc((size_t)G_*H_*2);
    unsigned short* w_ih1_b = (unsigned short*)alloc((size_t)G_*H_*2);
    _Float16*       w_hh0_h = (_Float16*)      alloc((size_t)G_*H_*2);
    _Float16*       w_hh1_h = (_Float16*)      alloc((size_t)G_*H_*2);
    unsigned short* w1_b    = (unsigned short*)alloc((size_t)128*H_*2);
    unsigned short* w2_b    = (unsigned short*)alloc((size_t)V_*128*2);
    float*          bias0   = (float*)         alloc((size_t)G_*4);
    float*          bias1   = (float*)         alloc((size_t)G_*4);
    unsigned short* emb     = (unsigned short*)alloc((size_t)M_*H_*2);
    unsigned short* h0b     = (unsigned short*)alloc((size_t)M_*H_*2);
    unsigned short* h1b     = (unsigned short*)alloc((size_t)M_*H_*2);
    unsigned short* hidb    = (unsigned short*)alloc((size_t)M_*128*2);
    float*          xp      = (float*)         alloc((size_t)M_*G_*4);

    prep_kernel<<<2048, 256, 0, stream>>>(w_ih0, w_hh0, b_ih0, b_hh0,
                                          w_ih1, w_hh1, b_ih1, b_hh1,
                                          w1, w2,
                                          w_ih0_b, w_hh0_h, w_ih1_b, w_hh1_h,
                                          w1_b, w2_b, bias0, bias1);
    embed_kernel<<<M_, 256, 0, stream>>>(src, w_emb, b_emb, emb);

    // x_proj0 = emb @ w_ih0^T + (b_ih0+b_hh0)   [8192,2048] fp32
    gemm_kernel<false,false><<<dim3(G_/128, M_/128), 256, 0, stream>>>(emb, w_ih0_b, bias0, xp, G_, H_);
    lstm_kernel<<<B_, 1024, 0, stream>>>(xp, (const uint4*)w_hh0_h, h0b);

    // x_proj1 = h0 @ w_ih1^T + (b_ih1+b_hh1)
    gemm_kernel<false,false><<<dim3(G_/128, M_/128), 256, 0, stream>>>(h0b, w_ih1_b, bias1, xp, G_, H_);
    lstm_kernel<<<B_, 1024, 0, stream>>>(xp, (const uint4*)w_hh1_h, h1b);

    // hid = relu(h1 @ w1^T + b1)   [8192,128] bf16
    gemm_kernel<true,true><<<dim3(1, M_/128), 256, 0, stream>>>(h1b, w1_b, b1, hidb, 128, H_);

    // logits = hid @ w2^T + b2     [8192,10000] fp32 -> d_out
    gemm_kernel<false,false><<<dim3((V_+127)/128, M_/128), 256, 0, stream>>>(hidb, w2_b, b2, out, V_, 128);
}

// Round 2
// 7157.584 us; speedup vs baseline: 2.3128x; 2.3128x over previous
//
#include <hip/hip_runtime.h>
#include <hip/hip_bf16.h>

#define B_ 16
#define S_ 512
#define H_ 512
#define V_ 10000
#define G_ 2048
#define M_ (B_*S_)   // 8192 tokens

typedef short bf16x8 __attribute__((ext_vector_type(8)));
typedef float f32x4 __attribute__((ext_vector_type(4)));
typedef _Float16 f16x8 __attribute__((ext_vector_type(8)));

static __device__ __forceinline__ unsigned short f2bf(float x) {
    union { float f; unsigned int u; } v; v.f = x;
    unsigned int r = v.u + 0x7fffu + ((v.u >> 16) & 1u);   // RNE
    return (unsigned short)(r >> 16);
}

static __device__ __forceinline__ unsigned short f2h_bits(float x) {
    _Float16 h = (_Float16)x;
    return __builtin_bit_cast(unsigned short, h);
}

// ---------------------------------------------------------------------------
// prep: fp32 weights -> bf16 (GEMM operands); w_hh -> f16 MFMA B-fragment
// layout per block: wfrag[j 16][kc 16][wrow 8][lane 64][e 8] halves.
//   local row r = wrow*16 + (lane&15); global gate row R = (r>>5)*512 + j*32 + (r&31)
//   k = kc*32 + (lane>>4)*8 + e
// Also combined biases b_ih + b_hh.
// ---------------------------------------------------------------------------
__global__ void prep_kernel(const float* __restrict__ w_ih0, const float* __restrict__ w_hh0,
                            const float* __restrict__ b_ih0, const float* __restrict__ b_hh0,
                            const float* __restrict__ w_ih1, const float* __restrict__ w_hh1,
                            const float* __restrict__ b_ih1, const float* __restrict__ b_hh1,
                            const float* __restrict__ w1,   const float* __restrict__ w2,
                            unsigned short* __restrict__ w_ih0_b, _Float16* __restrict__ wfrag0,
                            unsigned short* __restrict__ w_ih1_b, _Float16* __restrict__ wfrag1,
                            unsigned short* __restrict__ w1_b,    unsigned short* __restrict__ w2_b,
                            float* __restrict__ bias0, float* __restrict__ bias1) {
    int i  = blockIdx.x * blockDim.x + threadIdx.x;
    int st = gridDim.x * blockDim.x;
    for (int k = i; k < G_*H_; k += st) {
        w_ih0_b[k] = f2bf(w_ih0[k]);
        w_ih1_b[k] = f2bf(w_ih1[k]);
    }
    for (int d = i; d < G_*H_; d += st) {
        int e    = d & 7;
        int l    = (d >> 3) & 63;
        int wrow = (d >> 9) & 7;
        int kc   = (d >> 12) & 15;
        int j    = (d >> 16) & 15;
        int r    = wrow*16 + (l & 15);
        int R    = (r >> 5)*512 + j*32 + (r & 31);
        int k    = kc*32 + ((l >> 4) << 3) + e;
        int src  = R*H_ + k;
        wfrag0[d] = (_Float16)w_hh0[src];
        wfrag1[d] = (_Float16)w_hh1[src];
    }
    for (int k = i; k < V_*128; k += st) w2_b[k] = f2bf(w2[k]);
    for (int k = i; k < 128*H_; k += st) w1_b[k] = f2bf(w1[k]);
    for (int k = i; k < G_;     k += st) { bias0[k] = b_ih0[k] + b_hh0[k]; bias1[k] = b_ih1[k] + b_hh1[k]; }
}

// ---------------------------------------------------------------------------
// embed: emb[m][h] = w_emb[h][src[m]] + b_emb[h]  (bf16 out)
// ---------------------------------------------------------------------------
__global__ void embed_kernel(const int* __restrict__ src, const float* __restrict__ w_emb,
                             const float* __restrict__ b_emb, unsigned short* __restrict__ emb) {
    int m = blockIdx.x;
    int idx = src[m];
    for (int h = threadIdx.x; h < H_; h += blockDim.x)
        emb[(long)m*H_ + h] = f2bf(w_emb[(long)h*V_ + idx] + b_emb[h]);
}

// ---------------------------------------------------------------------------
// Generic bf16 MFMA GEMM: C[M,N] = A[M,K] @ B[N,K]^T + bias[N]
// ---------------------------------------------------------------------------
template<bool RELU, bool OUT_BF16>
__launch_bounds__(256)
__global__ void gemm_kernel(const unsigned short* __restrict__ A, const unsigned short* __restrict__ Bm,
                            const float* __restrict__ bias, void* __restrict__ Cout,
                            int Ndim, int K) {
    __shared__ unsigned short At[128*40];
    __shared__ unsigned short Bt[128*40];
    int m0 = blockIdx.y * 128;
    int n0 = blockIdx.x * 128;
    int tid  = threadIdx.x;
    int lane = tid & 63, wave = tid >> 6;
    int wm = (wave >> 1) * 64, wn = (wave & 1) * 64;
    int l15 = lane & 15, l4 = lane >> 4;
    f32x4 acc[4][4] = {};

    for (int kk = 0; kk < K; kk += 32) {
        __syncthreads();
        #pragma unroll
        for (int rep = 0; rep < 2; ++rep) {
            int gid = tid + rep*256;
            int row = gid >> 2, c8 = (gid & 3) << 3;
            *(uint4*)&At[row*40 + c8] = *(const uint4*)&A[(long)(m0+row)*K + kk + c8];
            int nrow = n0 + row; if (nrow >= Ndim) nrow = Ndim - 1;
            *(uint4*)&Bt[row*40 + c8] = *(const uint4*)&Bm[(long)nrow*K + kk + c8];
        }
        __syncthreads();
        bf16x8 af[4], bfr[4];
        #pragma unroll
        for (int i = 0; i < 4; ++i)
            af[i] = *(const bf16x8*)&At[(wm + i*16 + l15)*40 + l4*8];
        #pragma unroll
        for (int j = 0; j < 4; ++j)
            bfr[j] = *(const bf16x8*)&Bt[(wn + j*16 + l15)*40 + l4*8];
        #pragma unroll
        for (int i = 0; i < 4; ++i)
            #pragma unroll
            for (int j = 0; j < 4; ++j)
                acc[i][j] = __builtin_amdgcn_mfma_f32_16x16x32_bf16(af[i], bfr[j], acc[i][j], 0, 0, 0);
    }

    #pragma unroll
    for (int i = 0; i < 4; ++i) {
        int row = m0 + wm + i*16 + l4*4;
        #pragma unroll
        for (int j = 0; j < 4; ++j) {
            int col = n0 + wn + j*16 + l15;
            if (col < Ndim) {
                float bv = bias[col];
                #pragma unroll
                for (int r = 0; r < 4; ++r) {
                    float v = acc[i][j][r] + bv;
                    if (RELU) v = v > 0.f ? v : 0.f;
                    if (OUT_BF16) ((unsigned short*)Cout)[(long)(row+r)*Ndim + col] = f2bf(v);
                    else          ((float*)Cout)[(long)(row+r)*Ndim + col] = v;
                }
            }
        }
    }
}

// ---------------------------------------------------------------------------
// Cooperative LSTM layer: 16 blocks x 256 threads. Block j owns h cols
// [32j,32j+32) => gate rows {q*512 + j*32 + s : q<4, s<32} (128 rows).
// Weights LDS-resident (128 KB, f16 MFMA B-frags). Per step:
//   poll h(t-1) for all 16 chains from tagged u64 exchange words -> LDS
//   MFMA: gates[16 chains][128 rows] (wave w = quadrant w, 2 n-tiles)
//   elementwise: thread -> (chain, 2 cols): c in regs, h -> exchange + hout
// Tagged word: hi32 = tagbase + t + 1, lo32 = two f16 h. Poison 0xAA.. != tag.
// ---------------------------------------------------------------------------
__launch_bounds__(256)
__global__ void lstm_coop_kernel(const float* __restrict__ xp, const uint4* __restrict__ wfrag,
                                 unsigned long long* __restrict__ hexch,
                                 unsigned short* __restrict__ hout, int tagbase) {
    __shared__ uint4    w_lds[8192];        // 128 KB: [kc 16][wrow 8][lane 64] of 8 halves
    __shared__ _Float16 h_lds[16*520];      // chains x cols, padded stride
    __shared__ float    gbuf[16*132];       // chains x 128 gate rows, padded

    int j    = blockIdx.x;
    int tid  = threadIdx.x;
    int lane = tid & 63, wave = tid >> 6;
    int l15  = lane & 15, l4 = lane >> 4;

    for (int i = tid; i < 8192; i += 256) w_lds[i] = wfrag[(long)j*8192 + i];
    for (int i = tid; i < 4160; i += 256) ((unsigned int*)h_lds)[i] = 0;
    __syncthreads();

    const _Float16* wh = (const _Float16*)w_lds;

    // elementwise identity of this thread
    int em = tid >> 4, ecp = tid & 15;      // chain, col-pair within slice
    float c0 = 0.f, c1 = 0.f;

    for (int t = 0; t < S_; ++t) {
        // ---- poll exchange for h(t-1) ----
        if (t > 0) {
            unsigned int tagv = (unsigned int)(tagbase + t);
            const unsigned long long* src = hexch + (long)(t-1)*4096;
            unsigned long long v[16];
            #pragma unroll
            for (int q = 0; q < 16; ++q)
                v[q] = __hip_atomic_load(src + q*256 + tid, __ATOMIC_RELAXED, __HIP_MEMORY_SCOPE_AGENT);
            #pragma unroll
            for (int q = 0; q < 16; ++q) {
                while ((unsigned int)(v[q] >> 32) != tagv)
                    v[q] = __hip_atomic_load(src + q*256 + tid, __ATOMIC_RELAXED, __HIP_MEMORY_SCOPE_AGENT);
                // chain q, pair tid -> cols 2*tid, 2*tid+1
                *(unsigned int*)&h_lds[q*520 + tid*2] = (unsigned int)v[q];
            }
        }
        __syncthreads();

        // ---- MFMA: gates[m][rows of this block] ----
        {
            f32x4 acc[2] = {{0.f,0.f,0.f,0.f},{0.f,0.f,0.f,0.f}};
            #pragma unroll
            for (int kc = 0; kc < 16; ++kc) {
                f16x8 afrag = *(const f16x8*)&h_lds[l15*520 + kc*32 + l4*8];
                #pragma unroll
                for (int nt = 0; nt < 2; ++nt) {
                    f16x8 bfrag = *(const f16x8*)&wh[(((kc*8) + (wave*2+nt))*64 + lane)*8];
                    acc[nt] = __builtin_amdgcn_mfma_f32_16x16x32_f16(afrag, bfrag, acc[nt], 0, 0, 0);
                }
            }
            #pragma unroll
            for (int nt = 0; nt < 2; ++nt) {
                int row = wave*32 + nt*16 + l15;
                #pragma unroll
                for (int r = 0; r < 4; ++r)
                    gbuf[(l4*4 + r)*132 + row] = acc[nt][r];
            }
        }
        __syncthreads();

        // ---- elementwise: chain em, cols 32j+2ecp, 32j+2ecp+1 ----
        {
            int s0 = 2*ecp, s1 = 2*ecp + 1;
            const float* xr = xp + ((long)em*S_ + t)*G_ + j*32;
            const float* gb = gbuf + em*132;
            float xi0 = xr[s0]        + gb[s0];
            float xf0 = xr[512 + s0]  + gb[32 + s0];
            float xg0 = xr[1024 + s0] + gb[64 + s0];
            float xo0 = xr[1536 + s0] + gb[96 + s0];
            float xi1 = xr[s1]        + gb[s1];
            float xf1 = xr[512 + s1]  + gb[32 + s1];
            float xg1 = xr[1024 + s1] + gb[64 + s1];
            float xo1 = xr[1536 + s1] + gb[96 + s1];

            float i0 = 1.f/(1.f+__expf(-xi0)), f0 = 1.f/(1.f+__expf(-xf0));
            float g0 = tanhf(xg0),             o0 = 1.f/(1.f+__expf(-xo0));
            c0 = f0*c0 + i0*g0;
            float h0 = o0*tanhf(c0);

            float i1 = 1.f/(1.f+__expf(-xi1)), f1 = 1.f/(1.f+__expf(-xf1));
            float g1 = tanhf(xg1),             o1 = 1.f/(1.f+__expf(-xo1));
            c1 = f1*c1 + i1*g1;
            float h1 = o1*tanhf(c1);

            unsigned long long v = ((unsigned long long)(unsigned int)(tagbase + t + 1) << 32)
                                 | ((unsigned int)f2h_bits(h1) << 16) | f2h_bits(h0);
            __hip_atomic_store(&hexch[(long)t*4096 + em*256 + j*16 + ecp], v,
                               __ATOMIC_RELAXED, __HIP_MEMORY_SCOPE_AGENT);

            unsigned int u = ((unsigned int)f2bf(h1) << 16) | f2bf(h0);
            ((unsigned int*)hout)[((long)em*S_ + t)*256 + j*16 + ecp] = u;
        }
        // no barrier needed here: next poll writes h_lds only after barrier #1,
        // and gbuf rewrites only happen after barrier #1 of step t+1.
    }
}

// ---------------------------------------------------------------------------
extern "C" void kernel_launch(void* const* d_in, const int* in_sizes, int n_in,
                              void* d_out, int out_size, void* d_ws, size_t ws_size,
                              hipStream_t stream) {
    const int*   src   = (const int*)  d_in[0];
    const float* w_emb = (const float*)d_in[1];
    const float* b_emb = (const float*)d_in[2];
    const float* w_ih0 = (const float*)d_in[3];
    const float* w_hh0 = (const float*)d_in[4];
    const float* b_ih0 = (const float*)d_in[5];
    const float* b_hh0 = (const float*)d_in[6];
    const float* w_ih1 = (const float*)d_in[7];
    const float* w_hh1 = (const float*)d_in[8];
    const float* b_ih1 = (const float*)d_in[9];
    const float* b_hh1 = (const float*)d_in[10];
    const float* w1    = (const float*)d_in[11];
    const float* b1    = (const float*)d_in[12];
    const float* w2    = (const float*)d_in[13];
    const float* b2    = (const float*)d_in[14];
    float* out = (float*)d_out;

    char* ws = (char*)d_ws;
    size_t off = 0;
    auto alloc = [&](size_t bytes) -> void* {
        void* p = ws + off;
        off = (off + bytes + 255) & ~(size_t)255;
        return p;
    };
    unsigned short* w_ih0_b = (unsigned short*)alloc((size_t)G_*H_*2);
    unsigned short* w_ih1_b = (unsigned short*)alloc((size_t)G_*H_*2);
    _Float16*       wfrag0  = (_Float16*)      alloc((size_t)G_*H_*2);
    _Float16*       wfrag1  = (_Float16*)      alloc((size_t)G_*H_*2);
    unsigned short* w1_b    = (unsigned short*)alloc((size_t)128*H_*2);
    unsigned short* w2_b    = (unsigned short*)alloc((size_t)V_*128*2);
    float*          bias0   = (float*)         alloc((size_t)G_*4);
    float*          bias1   = (float*)         alloc((size_t)G_*4);
    unsigned short* emb     = (unsigned short*)alloc((size_t)M_*H_*2);
    unsigned short* h0b     = (unsigned short*)alloc((size_t)M_*H_*2);
    unsigned short* h1b     = (unsigned short*)alloc((size_t)M_*H_*2);
    unsigned short* hidb    = (unsigned short*)alloc((size_t)M_*128*2);
    float*          xp      = (float*)         alloc((size_t)M_*G_*4);
    unsigned long long* hexch = (unsigned long long*)alloc((size_t)S_*4096*8);  // 16 MB

    prep_kernel<<<2048, 256, 0, stream>>>(w_ih0, w_hh0, b_ih0, b_hh0,
                                          w_ih1, w_hh1, b_ih1, b_hh1,
                                          w1, w2,
                                          w_ih0_b, wfrag0, w_ih1_b, wfrag1,
                                          w1_b, w2_b, bias0, bias1);
    embed_kernel<<<M_, 256, 0, stream>>>(src, w_emb, b_emb, emb);

    // x_proj0 = emb @ w_ih0^T + (b_ih0+b_hh0)   [8192,2048] fp32
    gemm_kernel<false,false><<<dim3(G_/128, M_/128), 256, 0, stream>>>(emb, w_ih0_b, bias0, xp, G_, H_);
    lstm_coop_kernel<<<B_, 256, 0, stream>>>(xp, (const uint4*)wfrag0, hexch, h0b, 0);

    // x_proj1 = h0 @ w_ih1^T + (b_ih1+b_hh1)
    gemm_kernel<false,false><<<dim3(G_/128, M_/128), 256, 0, stream>>>(h0b, w_ih1_b, bias1, xp, G_, H_);
    lstm_coop_kernel<<<B_, 256, 0, stream>>>(xp, (const uint4*)wfrag1, hexch, h1b, 512);

    // hid = relu(h1 @ w1^T + b1)   [8192,128] bf16
    gemm_kernel<true,true><<<dim3(1, M_/128), 256, 0, stream>>>(h1b, w1_b, b1, hidb, 128, H_);

    // logits = hid @ w2^T + b2     [8192,10000] fp32 -> d_out
    gemm_kernel<false,false><<<dim3((V_+127)/128, M_/128), 256, 0, stream>>>(hidb, w2_b, b2, out, V_, 128);
}

// Round 3
// 2884.748 us; speedup vs baseline: 5.7385x; 2.4812x over previous
//
#include <hip/hip_runtime.h>
#include <hip/hip_bf16.h>

#define B_ 16
#define S_ 512
#define H_ 512
#define V_ 10000
#define G_ 2048
#define M_ (B_*S_)   // 8192 tokens

typedef short bf16x8 __attribute__((ext_vector_type(8)));
typedef float f32x4 __attribute__((ext_vector_type(4)));
typedef _Float16 f16x8 __attribute__((ext_vector_type(8)));

static __device__ __forceinline__ unsigned short f2bf(float x) {
    union { float f; unsigned int u; } v; v.f = x;
    unsigned int r = v.u + 0x7fffu + ((v.u >> 16) & 1u);   // RNE
    return (unsigned short)(r >> 16);
}
static __device__ __forceinline__ unsigned short f2h_bits(float x) {
    _Float16 h = (_Float16)x;
    return __builtin_bit_cast(unsigned short, h);
}

// ---------------------------------------------------------------------------
// prep:
//  - w_ih0 -> bf16 row-major (GEMM B operand)
//  - w_hh0 -> f16 MFMA B-frags, 16-block layout [j16][kc16][wrow8][lane64][e8]
//      r = wrow*16+(l&15); R = (r>>5)*512 + j*32 + (r&31); k = kc*32+(l>>4)*8+e
//  - w_ih1, w_hh1 -> f16 MFMA B-frags, 64-block layout [j64][kc16][nt2][lane64][e8]
//      r = nt*16+(l&15) (0..31); R = (r>>3)*512 + j*8 + (r&7); same k
//  - w1,w2 -> bf16; biases combined
// ---------------------------------------------------------------------------
__global__ void prep_kernel(const float* __restrict__ w_ih0, const float* __restrict__ w_hh0,
                            const float* __restrict__ b_ih0, const float* __restrict__ b_hh0,
                            const float* __restrict__ w_ih1, const float* __restrict__ w_hh1,
                            const float* __restrict__ b_ih1, const float* __restrict__ b_hh1,
                            const float* __restrict__ w1,   const float* __restrict__ w2,
                            unsigned short* __restrict__ w_ih0_b, _Float16* __restrict__ wfrag0,
                            _Float16* __restrict__ wfrag1x,      _Float16* __restrict__ wfrag1h,
                            unsigned short* __restrict__ w1_b,    unsigned short* __restrict__ w2_b,
                            float* __restrict__ bias0, float* __restrict__ bias1) {
    int i  = blockIdx.x * blockDim.x + threadIdx.x;
    int st = gridDim.x * blockDim.x;
    for (int k = i; k < G_*H_; k += st) w_ih0_b[k] = f2bf(w_ih0[k]);
    // layer-0 recurrent frags (16-block)
    for (int d = i; d < G_*H_; d += st) {
        int e    = d & 7;
        int l    = (d >> 3) & 63;
        int wrow = (d >> 9) & 7;
        int kc   = (d >> 12) & 15;
        int j    = (d >> 16) & 15;
        int r    = wrow*16 + (l & 15);
        int R    = (r >> 5)*512 + j*32 + (r & 31);
        int k    = kc*32 + ((l >> 4) << 3) + e;
        wfrag0[d] = (_Float16)w_hh0[R*H_ + k];
    }
    // layer-1 frags (64-block): both x-part (w_ih1) and h-part (w_hh1)
    for (int d = i; d < G_*H_; d += st) {
        int e    = d & 7;
        int l    = (d >> 3) & 63;
        int nt   = (d >> 9) & 1;
        int kc   = (d >> 10) & 15;
        int j    = (d >> 14) & 63;
        int r    = nt*16 + (l & 15);
        int R    = (r >> 3)*512 + j*8 + (r & 7);
        int k    = kc*32 + ((l >> 4) << 3) + e;
        wfrag1x[d] = (_Float16)w_ih1[R*H_ + k];
        wfrag1h[d] = (_Float16)w_hh1[R*H_ + k];
    }
    for (int k = i; k < V_*128; k += st) w2_b[k] = f2bf(w2[k]);
    for (int k = i; k < 128*H_; k += st) w1_b[k] = f2bf(w1[k]);
    for (int k = i; k < G_;     k += st) { bias0[k] = b_ih0[k] + b_hh0[k]; bias1[k] = b_ih1[k] + b_hh1[k]; }
}

// ---------------------------------------------------------------------------
__global__ void embed_kernel(const int* __restrict__ src, const float* __restrict__ w_emb,
                             const float* __restrict__ b_emb, unsigned short* __restrict__ emb) {
    int m = blockIdx.x;
    int idx = src[m];
    for (int h = threadIdx.x; h < H_; h += blockDim.x)
        emb[(long)m*H_ + h] = f2bf(w_emb[(long)h*V_ + idx] + b_emb[h]);
}

// ---------------------------------------------------------------------------
// Generic bf16 MFMA GEMM: C[M,N] = A[M,K] @ B[N,K]^T + bias[N]
// ---------------------------------------------------------------------------
template<bool RELU, bool OUT_BF16>
__launch_bounds__(256)
__global__ void gemm_kernel(const unsigned short* __restrict__ A, const unsigned short* __restrict__ Bm,
                            const float* __restrict__ bias, void* __restrict__ Cout,
                            int Ndim, int K) {
    __shared__ unsigned short At[128*40];
    __shared__ unsigned short Bt[128*40];
    int m0 = blockIdx.y * 128;
    int n0 = blockIdx.x * 128;
    int tid  = threadIdx.x;
    int lane = tid & 63, wave = tid >> 6;
    int wm = (wave >> 1) * 64, wn = (wave & 1) * 64;
    int l15 = lane & 15, l4 = lane >> 4;
    f32x4 acc[4][4] = {};

    for (int kk = 0; kk < K; kk += 32) {
        __syncthreads();
        #pragma unroll
        for (int rep = 0; rep < 2; ++rep) {
            int gid = tid + rep*256;
            int row = gid >> 2, c8 = (gid & 3) << 3;
            *(uint4*)&At[row*40 + c8] = *(const uint4*)&A[(long)(m0+row)*K + kk + c8];
            int nrow = n0 + row; if (nrow >= Ndim) nrow = Ndim - 1;
            *(uint4*)&Bt[row*40 + c8] = *(const uint4*)&Bm[(long)nrow*K + kk + c8];
        }
        __syncthreads();
        bf16x8 af[4], bfr[4];
        #pragma unroll
        for (int i = 0; i < 4; ++i)
            af[i] = *(const bf16x8*)&At[(wm + i*16 + l15)*40 + l4*8];
        #pragma unroll
        for (int j = 0; j < 4; ++j)
            bfr[j] = *(const bf16x8*)&Bt[(wn + j*16 + l15)*40 + l4*8];
        #pragma unroll
        for (int i = 0; i < 4; ++i)
            #pragma unroll
            for (int j = 0; j < 4; ++j)
                acc[i][j] = __builtin_amdgcn_mfma_f32_16x16x32_bf16(af[i], bfr[j], acc[i][j], 0, 0, 0);
    }

    #pragma unroll
    for (int i = 0; i < 4; ++i) {
        int row = m0 + wm + i*16 + l4*4;
        #pragma unroll
        for (int j = 0; j < 4; ++j) {
            int col = n0 + wn + j*16 + l15;
            if (col < Ndim) {
                float bv = bias[col];
                #pragma unroll
                for (int r = 0; r < 4; ++r) {
                    float v = acc[i][j][r] + bv;
                    if (RELU) v = v > 0.f ? v : 0.f;
                    if (OUT_BF16) ((unsigned short*)Cout)[(long)(row+r)*Ndim + col] = f2bf(v);
                    else          ((float*)Cout)[(long)(row+r)*Ndim + col] = v;
                }
            }
        }
    }
}

// ---------------------------------------------------------------------------
// Fused 2-layer wavefront-pipelined LSTM.
//  Blocks 0..15  : layer 0, block j owns h0 cols [32j,32j+32) (128 gate rows).
//  Blocks 16..79 : layer 1, block j1 owns h1 cols [8j1,8j1+8) (32 gate rows);
//                  computes x-part (h0_t @ w_ih1^T) AND h-part on the fly.
//  Exchange: tagged u64 (hi32 = t+1, lo32 = two f16). Poison 0xAA.. != tag.
//  512 threads/block: poll chain = 8 u64/slab/thread; s_sleep backoff.
// ---------------------------------------------------------------------------
__launch_bounds__(512)
__global__ void lstm_fused_kernel(const float* __restrict__ xp,
                                  const uint4* __restrict__ wfrag0,
                                  const uint4* __restrict__ wfrag1x,
                                  const uint4* __restrict__ wfrag1h,
                                  const float* __restrict__ bias1,
                                  unsigned long long* __restrict__ h0ex,
                                  unsigned long long* __restrict__ h1ex,
                                  unsigned short* __restrict__ hout) {
    __shared__ __align__(16) char smem[156160];
    int tid  = threadIdx.x;
    int lane = tid & 63, wave = tid >> 6;
    int l15  = lane & 15, l4 = lane >> 4;

    if (blockIdx.x < 16) {
        // ================= layer 0 =================
        uint4*     w_lds = (uint4*)smem;                       // [kc16][wrow8][lane64] of 8 halves
        _Float16*  h_lds = (_Float16*)(smem + 131072);         // [16][520]
        float*     gbuf  = (float*)(smem + 131072 + 16640);    // [16][132]
        int j = blockIdx.x;
        for (int i = tid; i < 8192; i += 512) w_lds[i] = wfrag0[(long)j*8192 + i];
        for (int i = tid; i < 4160; i += 512) ((unsigned int*)h_lds)[i] = 0;
        __syncthreads();
        const _Float16* wh = (const _Float16*)w_lds;
        int ch = tid >> 5, s = tid & 31;    // elementwise: chain, col-in-slice
        float c = 0.f;

        for (int t = 0; t < S_; ++t) {
            const float* xr = xp + ((long)ch*S_ + t)*G_ + j*32 + s;   // hoisted loads
            float xi = xr[0], xf = xr[512], xg = xr[1024], xo = xr[1536];
            if (t > 0) {
                unsigned int tagv = (unsigned int)t;
                const unsigned long long* base = h0ex + (long)(t-1)*4096;
                unsigned long long v[8];
                #pragma unroll
                for (int q = 0; q < 8; ++q)
                    v[q] = __hip_atomic_load(base + q*512 + tid, __ATOMIC_RELAXED, __HIP_MEMORY_SCOPE_AGENT);
                #pragma unroll
                for (int q = 0; q < 8; ++q) {
                    while ((unsigned int)(v[q] >> 32) != tagv) {
                        __builtin_amdgcn_s_sleep(1);
                        v[q] = __hip_atomic_load(base + q*512 + tid, __ATOMIC_RELAXED, __HIP_MEMORY_SCOPE_AGENT);
                    }
                    int w = q*512 + tid;
                    *(unsigned int*)&h_lds[(w >> 8)*520 + (w & 255)*2] = (unsigned int)v[q];
                }
            }
            __syncthreads();
            f32x4 acc = {0.f,0.f,0.f,0.f};
            #pragma unroll
            for (int kc = 0; kc < 16; ++kc) {
                f16x8 af = *(const f16x8*)&h_lds[l15*520 + kc*32 + l4*8];
                f16x8 bf = *(const f16x8*)&wh[(((kc*8) + wave)*64 + lane)*8];
                acc = __builtin_amdgcn_mfma_f32_16x16x32_f16(af, bf, acc, 0, 0, 0);
            }
            #pragma unroll
            for (int r = 0; r < 4; ++r)
                gbuf[(l4*4 + r)*132 + wave*16 + l15] = acc[r];
            __syncthreads();
            const float* gb = gbuf + ch*132;
            xi += gb[s]; xf += gb[32+s]; xg += gb[64+s]; xo += gb[96+s];
            float ig = 1.f/(1.f+__expf(-xi));
            float fg = 1.f/(1.f+__expf(-xf));
            float gg = tanhf(xg);
            float og = 1.f/(1.f+__expf(-xo));
            c = fg*c + ig*gg;
            float h = og*tanhf(c);
            unsigned int me = f2h_bits(h);
            unsigned int up = (unsigned int)__shfl_down((int)me, 1, 64);
            if (!(s & 1)) {
                unsigned long long vv = ((unsigned long long)(unsigned int)(t+1) << 32)
                                      | (up << 16) | me;
                __hip_atomic_store(&h0ex[(long)t*4096 + ch*256 + j*16 + (s>>1)], vv,
                                   __ATOMIC_RELAXED, __HIP_MEMORY_SCOPE_AGENT);
            }
        }
    } else {
        // ================= layer 1 =================
        uint4*     wx   = (uint4*)smem;                        // [kc16][nt2][lane64] (x-part)
        uint4*     whh  = wx + 2048;                           // (h-part)
        _Float16*  h0l  = (_Float16*)(smem + 65536);           // [16][520]
        _Float16*  h1l  = h0l + 16*520;
        float*     gbuf = (float*)(smem + 65536 + 2*16640);    // [src2][kh2][16][36]
        float*     bl   = gbuf + 2*2*16*36;                    // [32]
        int j1 = blockIdx.x - 16;
        for (int i = tid; i < 2048; i += 512) {
            wx[i]  = wfrag1x[(long)j1*2048 + i];
            whh[i] = wfrag1h[(long)j1*2048 + i];
        }
        if (tid < 32) bl[tid] = bias1[(tid >> 3)*512 + j1*8 + (tid & 7)];
        for (int i = tid; i < 8320; i += 512) ((unsigned int*)h0l)[i] = 0;   // zero h0l+h1l
        __syncthreads();
        int ch = tid >> 3, sc = tid & 7;    // elementwise ids (tid<128)
        float c = 0.f;

        for (int t = 0; t < S_; ++t) {
            {   // poll h0 slab t (tag t+1) and h1 slab t-1 (tag t)
                unsigned int tag0 = (unsigned int)(t+1);
                const unsigned long long* b0 = h0ex + (long)t*4096;
                unsigned long long v0[8], v1[8];
                #pragma unroll
                for (int q = 0; q < 8; ++q)
                    v0[q] = __hip_atomic_load(b0 + q*512 + tid, __ATOMIC_RELAXED, __HIP_MEMORY_SCOPE_AGENT);
                if (t > 0) {
                    const unsigned long long* b1 = h1ex + (long)(t-1)*4096;
                    #pragma unroll
                    for (int q = 0; q < 8; ++q)
                        v1[q] = __hip_atomic_load(b1 + q*512 + tid, __ATOMIC_RELAXED, __HIP_MEMORY_SCOPE_AGENT);
                    unsigned int tag1 = (unsigned int)t;
                    #pragma unroll
                    for (int q = 0; q < 8; ++q) {
                        while ((unsigned int)(v1[q] >> 32) != tag1) {
                            __builtin_amdgcn_s_sleep(1);
                            v1[q] = __hip_atomic_load(b1 + q*512 + tid, __ATOMIC_RELAXED, __HIP_MEMORY_SCOPE_AGENT);
                        }
                        int w = q*512 + tid;
                        *(unsigned int*)&h1l[(w >> 8)*520 + (w & 255)*2] = (unsigned int)v1[q];
                    }
                }
                #pragma unroll
                for (int q = 0; q < 8; ++q) {
                    while ((unsigned int)(v0[q] >> 32) != tag0) {
                        __builtin_amdgcn_s_sleep(1);
                        v0[q] = __hip_atomic_load(b0 + q*512 + tid, __ATOMIC_RELAXED, __HIP_MEMORY_SCOPE_AGENT);
                    }
                    int w = q*512 + tid;
                    *(unsigned int*)&h0l[(w >> 8)*520 + (w & 255)*2] = (unsigned int)v0[q];
                }
            }
            __syncthreads();
            {   // MFMA: wave -> (src, nt, kc-half); 8 MFMA each
                int src = wave >> 2, nt = (wave >> 1) & 1, kh = wave & 1;
                const _Float16* hs = src ? h1l : h0l;
                const _Float16* ws = (const _Float16*)(src ? whh : wx);
                f32x4 acc = {0.f,0.f,0.f,0.f};
                #pragma unroll
                for (int k2 = 0; k2 < 8; ++k2) {
                    int kc = kh*8 + k2;
                    f16x8 af = *(const f16x8*)&hs[l15*520 + kc*32 + l4*8];
                    f16x8 bf = *(const f16x8*)&ws[((kc*2 + nt)*64 + lane)*8];
                    acc = __builtin_amdgcn_mfma_f32_16x16x32_f16(af, bf, acc, 0, 0, 0);
                }
                #pragma unroll
                for (int r = 0; r < 4; ++r)
                    gbuf[((src*2 + kh)*16 + (l4*4 + r))*36 + nt*16 + l15] = acc[r];
            }
            __syncthreads();
            if (tid < 128) {
                const float* g0 = gbuf + (0*16 + ch)*36;
                const float* g1 = gbuf + (1*16 + ch)*36;
                const float* g2 = gbuf + (2*16 + ch)*36;
                const float* g3 = gbuf + (3*16 + ch)*36;
                float xi = g0[sc]    + g1[sc]    + g2[sc]    + g3[sc]    + bl[sc];
                float xf = g0[8+sc]  + g1[8+sc]  + g2[8+sc]  + g3[8+sc]  + bl[8+sc];
                float xg = g0[16+sc] + g1[16+sc] + g2[16+sc] + g3[16+sc] + bl[16+sc];
                float xo = g0[24+sc] + g1[24+sc] + g2[24+sc] + g3[24+sc] + bl[24+sc];
                float ig = 1.f/(1.f+__expf(-xi));
                float fg = 1.f/(1.f+__expf(-xf));
                float gg = tanhf(xg);
                float og = 1.f/(1.f+__expf(-xo));
                c = fg*c + ig*gg;
                float h = og*tanhf(c);
                hout[((long)ch*S_ + t)*H_ + j1*8 + sc] = f2bf(h);
                unsigned int me = f2h_bits(h);
                unsigned int up = (unsigned int)__shfl_down((int)me, 1, 64);
                if (!(sc & 1)) {
                    unsigned long long vv = ((unsigned long long)(unsigned int)(t+1) << 32)
                                          | (up << 16) | me;
                    __hip_atomic_store(&h1ex[(long)t*4096 + ch*256 + j1*4 + (sc>>1)], vv,
                                       __ATOMIC_RELAXED, __HIP_MEMORY_SCOPE_AGENT);
                }
            }
        }
    }
}

// ---------------------------------------------------------------------------
extern "C" void kernel_launch(void* const* d_in, const int* in_sizes, int n_in,
                              void* d_out, int out_size, void* d_ws, size_t ws_size,
                              hipStream_t stream) {
    const int*   src   = (const int*)  d_in[0];
    const float* w_emb = (const float*)d_in[1];
    const float* b_emb = (const float*)d_in[2];
    const float* w_ih0 = (const float*)d_in[3];
    const float* w_hh0 = (const float*)d_in[4];
    const float* b_ih0 = (const float*)d_in[5];
    const float* b_hh0 = (const float*)d_in[6];
    const float* w_ih1 = (const float*)d_in[7];
    const float* w_hh1 = (const float*)d_in[8];
    const float* b_ih1 = (const float*)d_in[9];
    const float* b_hh1 = (const float*)d_in[10];
    const float* w1    = (const float*)d_in[11];
    const float* b1    = (const float*)d_in[12];
    const float* w2    = (const float*)d_in[13];
    const float* b2    = (const float*)d_in[14];
    float* out = (float*)d_out;

    char* ws = (char*)d_ws;
    size_t off = 0;
    auto alloc = [&](size_t bytes) -> void* {
        void* p = ws + off;
        off = (off + bytes + 255) & ~(size_t)255;
        return p;
    };
    unsigned short* w_ih0_b = (unsigned short*)alloc((size_t)G_*H_*2);
    _Float16*       wfrag0  = (_Float16*)      alloc((size_t)G_*H_*2);
    _Float16*       wfrag1x = (_Float16*)      alloc((size_t)G_*H_*2);
    _Float16*       wfrag1h = (_Float16*)      alloc((size_t)G_*H_*2);
    unsigned short* w1_b    = (unsigned short*)alloc((size_t)128*H_*2);
    unsigned short* w2_b    = (unsigned short*)alloc((size_t)V_*128*2);
    float*          bias0   = (float*)         alloc((size_t)G_*4);
    float*          bias1   = (float*)         alloc((size_t)G_*4);
    unsigned short* emb     = (unsigned short*)alloc((size_t)M_*H_*2);   // reused as hout (h1)
    unsigned short* hidb    = (unsigned short*)alloc((size_t)M_*128*2);
    float*          xp      = (float*)         alloc((size_t)M_*G_*4);
    unsigned long long* h0ex = (unsigned long long*)alloc((size_t)S_*4096*8);  // 16 MB
    unsigned long long* h1ex = (unsigned long long*)alloc((size_t)S_*4096*8);  // 16 MB

    prep_kernel<<<2048, 256, 0, stream>>>(w_ih0, w_hh0, b_ih0, b_hh0,
                                          w_ih1, w_hh1, b_ih1, b_hh1,
                                          w1, w2,
                                          w_ih0_b, wfrag0, wfrag1x, wfrag1h,
                                          w1_b, w2_b, bias0, bias1);
    embed_kernel<<<M_, 256, 0, stream>>>(src, w_emb, b_emb, emb);

    // x_proj0 = emb @ w_ih0^T + (b_ih0+b_hh0)   [8192,2048] fp32
    gemm_kernel<false,false><<<dim3(G_/128, M_/128), 256, 0, stream>>>(emb, w_ih0_b, bias0, xp, G_, H_);

    // fused 2-layer pipelined LSTM; h1 (bf16) lands in `emb` buffer (reuse)
    lstm_fused_kernel<<<80, 512, 0, stream>>>(xp, (const uint4*)wfrag0,
                                              (const uint4*)wfrag1x, (const uint4*)wfrag1h,
                                              bias1, h0ex, h1ex, emb);

    // hid = relu(h1 @ w1^T + b1)   [8192,128] bf16
    gemm_kernel<true,true><<<dim3(1, M_/128), 256, 0, stream>>>(emb, w1_b, b1, hidb, 128, H_);

    // logits = hid @ w2^T + b2     [8192,10000] fp32 -> d_out
    gemm_kernel<false,false><<<dim3((V_+127)/128, M_/128), 256, 0, stream>>>(hidb, w2_b, b2, out, V_, 128);
}